// Round 8
// baseline (4331.816 us; speedup 1.0000x reference)
//
#include <hip/hip_runtime.h>

#define N_AUTHOR 100000
#define N_FOS    30000
#define N_INST   8000
#define N_PAPER  200000
#define NCNT     838000
#define ETOT     3300000
#define NBKT     1637

typedef __attribute__((ext_vector_type(8))) short short8v;
typedef __attribute__((ext_vector_type(4))) float float4v;

__device__ __forceinline__ unsigned short f2bf(float f) {
  unsigned u = __float_as_uint(f);
  u = u + 0x7fffu + ((u >> 16) & 1u);
  return (unsigned short)(u >> 16);
}
#define BF2F(s) __uint_as_float(((unsigned)(unsigned short)(s)) << 16)

__device__ __forceinline__ void acc8(float4v& x, float4v& y, short8v h) {
  x[0] += BF2F(h[0]); x[1] += BF2F(h[1]); x[2] += BF2F(h[2]); x[3] += BF2F(h[3]);
  y[0] += BF2F(h[4]); y[1] += BF2F(h[5]); y[2] += BF2F(h[6]); y[3] += BF2F(h[7]);
}

// ---------------- workspace layout (bytes) ----------------
#define O_CNT    0
#define O_OFFS   3352000
#define O_CURSOR 6704000      // doubles as bktCur (new path) / cursor (fallback)
#define O_BTOT   10056000
#define O_CSR    10060096
#define O_WT     23260096
#define XB_AUTHOR 23620544
#define XB_FOS    49220544
#define XB_INST   56900544
#define XB_PAPER  58948544
#define O_AGG     110148544
#define WS_NEED_BF  110148544ULL
#define WS_NEED_AGG 324676544ULL

struct RelTab { const int* src; const int* dst; int E; int base; };
struct Rels { RelTab r[7]; };
struct WPtrs { const float* w[11]; };
struct XCvt { const float* x; unsigned short* xb; int n8; };

// merged prep: W transpose+bf16, x fp32->bf16, edge COUNT (cnt pre-zeroed)
__global__ void prep(WPtrs P, unsigned short* __restrict__ wt,
                     int* __restrict__ cnt, XCvt x0, XCvt x1, XCvt x2, XCvt x3,
                     Rels R, int doX) {
  int gsz = gridDim.x * blockDim.x;
  int gtid = blockIdx.x * blockDim.x + threadIdx.x;
  for (int i = gtid; i < 11 * 16384; i += gsz) {
    int mat = i >> 14, rem = i & 16383;
    int k = rem >> 7, n = rem & 127;
    wt[mat * 16384 + n * 128 + k] = f2bf(P.w[mat][rem]);
  }
  if (doX) {
    XCvt xc[4] = {x0, x1, x2, x3};
    #pragma unroll
    for (int a = 0; a < 4; ++a) {
      const float* xp = xc[a].x;
      short8v* xbp = (short8v*)xc[a].xb;
      int n8 = xc[a].n8;
      for (int i = gtid; i < n8; i += gsz) {
        float4v v0 = *(const float4v*)(xp + (size_t)i * 8);
        float4v v1 = *(const float4v*)(xp + (size_t)i * 8 + 4);
        short8v h;
        h[0] = (short)f2bf(v0[0]); h[1] = (short)f2bf(v0[1]);
        h[2] = (short)f2bf(v0[2]); h[3] = (short)f2bf(v0[3]);
        h[4] = (short)f2bf(v1[0]); h[5] = (short)f2bf(v1[1]);
        h[6] = (short)f2bf(v1[2]); h[7] = (short)f2bf(v1[3]);
        xbp[i] = h;
      }
    }
  }
  #pragma unroll
  for (int rr = 0; rr < 7; ++rr) {
    const int* dst = R.r[rr].dst;
    int E = R.r[rr].E, base = R.r[rr].base;
    for (int e = gtid; e < E; e += gsz) atomicAdd(&cnt[base + dst[e]], 1);
  }
}

__global__ void scan1(const int* __restrict__ cnt, int* __restrict__ offs,
                      int* __restrict__ btot, int n) {
  __shared__ int sh[256];
  int tid = threadIdx.x;
  int base = blockIdx.x * 2048 + tid * 8;
  int v[8]; int s = 0;
  #pragma unroll
  for (int i = 0; i < 8; ++i) { v[i] = (base + i < n) ? cnt[base + i] : 0; s += v[i]; }
  sh[tid] = s; __syncthreads();
  for (int off = 1; off < 256; off <<= 1) {
    int t = (tid >= off) ? sh[tid - off] : 0;
    __syncthreads();
    sh[tid] += t;
    __syncthreads();
  }
  int excl = sh[tid] - s;
  if (tid == 255) btot[blockIdx.x] = sh[255];
  int run = excl;
  #pragma unroll
  for (int i = 0; i < 8; ++i) { if (base + i < n) offs[base + i] = run; run += v[i]; }
}

// scan23: finalize offs; also init bktCur[b] = offs[b*512]
__global__ void scan23(int* __restrict__ offs, int* __restrict__ bktCur,
                       const int* __restrict__ btot, int nb, int n) {
  __shared__ int sh[512];
  int tid = threadIdx.x;
  int v = (tid < nb) ? btot[tid] : 0;
  sh[tid] = v; __syncthreads();
  for (int off = 1; off < 512; off <<= 1) {
    int t = (tid >= off) ? sh[tid - off] : 0;
    __syncthreads();
    sh[tid] += t;
    __syncthreads();
  }
  int excl = sh[tid] - v;
  __syncthreads();
  sh[tid] = excl;
  __syncthreads();
  int gsz = gridDim.x * 512;
  for (int idx = blockIdx.x * 512 + tid; idx < n; idx += gsz) {
    int val = offs[idx] + sh[idx >> 11];
    offs[idx] = val;
    if ((idx & 511) == 0) bktCur[idx >> 9] = val;
  }
}

// C1: XCD-affine pair scatter. 2048 blocks = 8 classes x 256 sub-blocks.
__global__ __launch_bounds__(256, 8) void c1_scatter(Rels R,
    int* __restrict__ bktCur, uint2* __restrict__ pairs) {
  const int cls = blockIdx.x & 7;
  const int sub = blockIdx.x >> 3;              // 0..255
  const int stride = (gridDim.x >> 3) * 256;    // 65536
  const int t0 = sub * 256 + threadIdx.x;
  #pragma unroll
  for (int rr = 0; rr < 7; ++rr) {
    const int* __restrict__ dst = R.r[rr].dst;
    const int* __restrict__ src = R.r[rr].src;
    const int E = R.r[rr].E, base = R.r[rr].base;
    for (int e = t0; e < E; e += stride) {
      int gd = base + dst[e];
      int b = gd >> 9;
      if ((b & 7) == cls) {
        int s = src[e];
        int pos = atomicAdd(&bktCur[b], 1);
        pairs[pos] = uint2{(unsigned)s, (unsigned)gd};
      }
    }
  }
}

// C2: per-bucket CSR build (contiguous writes, LDS ranks)
__global__ __launch_bounds__(256, 8) void c2_build(
    const uint2* __restrict__ pairs, const int* __restrict__ offs,
    int* __restrict__ csr) {
  __shared__ int rank[512];
  const int b = blockIdx.x;
  const int dbase = b << 9;
  for (int i = threadIdx.x; i < 512; i += 256) rank[i] = 0;
  __syncthreads();
  const int start = offs[dbase];
  const int end = (dbase + 512 < NCNT) ? offs[dbase + 512] : ETOT;
  for (int i = start + threadIdx.x; i < end; i += 256) {
    uint2 p = pairs[i];
    int gd = (int)p.y;
    int r = atomicAdd(&rank[gd - dbase], 1);
    csr[offs[gd] + r] = (int)p.x;
  }
}

// ---------------- single-launch aggregation (uniform-branch xb select) ------
__global__ __launch_bounds__(256, 8) void agg_all(
    const unsigned short* __restrict__ xbA, const unsigned short* __restrict__ xbF,
    const unsigned short* __restrict__ xbI, const unsigned short* __restrict__ xbP,
    const int* __restrict__ offs, const int* __restrict__ cnt,
    const int* __restrict__ csr, unsigned short* __restrict__ agg) {
  const int w = blockIdx.x * 4 + (threadIdx.x >> 6);
  if (w >= NCNT) return;
  const unsigned short* xb;
  if (w < 8000) xb = xbA;            // aff: author -> inst
  else if (w < 108000) xb = xbI;     // ita: inst -> author
  else if (w < 308000) xb = xbA;     // writes: author -> paper
  else if (w < 638000) xb = xbP;     // pta/cites/topic: paper -> *
  else xb = xbF;                     // ftp: fos -> paper
  const int lane = threadIdx.x & 63;
  const int st = offs[w];
  const int deg = cnt[w];
  const int ce = lane * 2;
  float a0 = 0.f, a1 = 0.f;
  for (int j = 0; j < deg; j += 8) {
    int rem = deg - j;
    int nb = (rem > 8) ? 8 : rem;
    int vidx = 0;
    if (lane < nb) vidx = csr[st + j + lane];
    unsigned r0 = 0, r1 = 0, r2 = 0, r3 = 0, r4 = 0, r5 = 0, r6 = 0, r7 = 0;
    int s;
    if (nb > 0) { s = __builtin_amdgcn_readlane(vidx, 0); r0 = *(const unsigned*)(xb + (size_t)s * 128 + ce); }
    if (nb > 1) { s = __builtin_amdgcn_readlane(vidx, 1); r1 = *(const unsigned*)(xb + (size_t)s * 128 + ce); }
    if (nb > 2) { s = __builtin_amdgcn_readlane(vidx, 2); r2 = *(const unsigned*)(xb + (size_t)s * 128 + ce); }
    if (nb > 3) { s = __builtin_amdgcn_readlane(vidx, 3); r3 = *(const unsigned*)(xb + (size_t)s * 128 + ce); }
    if (nb > 4) { s = __builtin_amdgcn_readlane(vidx, 4); r4 = *(const unsigned*)(xb + (size_t)s * 128 + ce); }
    if (nb > 5) { s = __builtin_amdgcn_readlane(vidx, 5); r5 = *(const unsigned*)(xb + (size_t)s * 128 + ce); }
    if (nb > 6) { s = __builtin_amdgcn_readlane(vidx, 6); r6 = *(const unsigned*)(xb + (size_t)s * 128 + ce); }
    if (nb > 7) { s = __builtin_amdgcn_readlane(vidx, 7); r7 = *(const unsigned*)(xb + (size_t)s * 128 + ce); }
    if (nb > 0) { a0 += __uint_as_float(r0 << 16); a1 += __uint_as_float(r0 & 0xffff0000u); }
    if (nb > 1) { a0 += __uint_as_float(r1 << 16); a1 += __uint_as_float(r1 & 0xffff0000u); }
    if (nb > 2) { a0 += __uint_as_float(r2 << 16); a1 += __uint_as_float(r2 & 0xffff0000u); }
    if (nb > 3) { a0 += __uint_as_float(r3 << 16); a1 += __uint_as_float(r3 & 0xffff0000u); }
    if (nb > 4) { a0 += __uint_as_float(r4 << 16); a1 += __uint_as_float(r4 & 0xffff0000u); }
    if (nb > 5) { a0 += __uint_as_float(r5 << 16); a1 += __uint_as_float(r5 & 0xffff0000u); }
    if (nb > 6) { a0 += __uint_as_float(r6 << 16); a1 += __uint_as_float(r6 & 0xffff0000u); }
    if (nb > 7) { a0 += __uint_as_float(r7 << 16); a1 += __uint_as_float(r7 & 0xffff0000u); }
  }
  float sc = 1.0f / (float)((deg > 0) ? deg : 1);
  unsigned h0 = f2bf(a0 * sc), h1 = f2bf(a1 * sc);
  *(unsigned*)(agg + (size_t)w * 128 + ce) = h0 | (h1 << 16);
}

// ---------------- per-type streaming GEMM (scalar args, full unroll) --------
template <int NSRC>
__global__ __launch_bounds__(256, 4) void gemm_t(
    const unsigned short* __restrict__ s0, const unsigned short* __restrict__ s1,
    const unsigned short* __restrict__ s2, const unsigned short* __restrict__ s3,
    const unsigned short* __restrict__ w0, const unsigned short* __restrict__ w1,
    const unsigned short* __restrict__ w2, const unsigned short* __restrict__ w3,
    const float* __restrict__ bias, float* __restrict__ out, int n) {
  const int lane = threadIdx.x & 63;
  const int wv = threadIdx.x >> 6;
  const int rb = blockIdx.x * 64 + wv * 16;
  int ar = rb + (lane & 15); if (ar >= n) ar = n - 1;
  const int ch = lane >> 4;

  const unsigned short* sp[4] = {s0, s1, s2, s3};
  const unsigned short* wp[4] = {w0, w1, w2, w3};

  float4v acc[8];
  #pragma unroll
  for (int i = 0; i < 8; ++i) acc[i] = (float4v)0.0f;

  #pragma unroll
  for (int kb = 0; kb < NSRC; ++kb) {
    const unsigned short* ab = sp[kb] + (size_t)ar * 128 + ch * 8;
    short8v af[4];
    #pragma unroll
    for (int ks = 0; ks < 4; ++ks)
      af[ks] = *(const short8v*)(ab + ks * 32);
    const unsigned short* wb = wp[kb] + (size_t)(lane & 15) * 128 + ch * 8;
    #pragma unroll
    for (int ct = 0; ct < 8; ++ct) {
      short8v bfr[4];
      #pragma unroll
      for (int ks = 0; ks < 4; ++ks)
        bfr[ks] = *(const short8v*)(wb + ct * 2048 + ks * 32);
      #pragma unroll
      for (int ks = 0; ks < 4; ++ks)
        acc[ct] = __builtin_amdgcn_mfma_f32_16x16x32_bf16(af[ks], bfr[ks], acc[ct], 0, 0, 0);
    }
  }
  #pragma unroll
  for (int ct = 0; ct < 8; ++ct) {
    #pragma unroll
    for (int i = 0; i < 4; ++i) {
      int g = rb + (lane >> 4) * 4 + i;
      if (g < n) {
        int col = ct * 16 + (lane & 15);
        out[(size_t)g * 128 + col] = acc[ct][i] + bias[col];
      }
    }
  }
}

// ---------------- fallback: old fill + fused kernel (ws too small) ----------
__global__ void fill_k(Rels R, int* __restrict__ cursor, int* __restrict__ csr) {
  int gsz = gridDim.x * blockDim.x;
  int gtid = blockIdx.x * blockDim.x + threadIdx.x;
  #pragma unroll
  for (int rr = 0; rr < 7; ++rr) {
    const int* src = R.r[rr].src;
    const int* dst = R.r[rr].dst;
    int E = R.r[rr].E, base = R.r[rr].base;
    for (int e = gtid; e < E; e += gsz) {
      int p = atomicAdd(&cursor[base + dst[e]], 1);
      csr[p] = src[e];
    }
  }
}

__global__ void cpy_cursor(const int* __restrict__ offs, int* __restrict__ cursor) {
  int i = blockIdx.x * 256 + threadIdx.x;
  if (i < NCNT) cursor[i] = offs[i];
}

struct GemmSrc { const float* x; const unsigned short* xb;
                 const unsigned short* wt; int cntBase; };
struct TypeArgs {
  GemmSrc s[4];
  int nsrc, bstart, n;
  const float* bias;
  float* out;
};
struct AllArgs {
  TypeArgs t[4];
  const int* offs;
  const int* cnt;
  const int* csr;
};

__global__ __launch_bounds__(256, 4) void rgcn_gemm(AllArgs A) {
  __shared__ unsigned short a_lds[64 * 128];
  const int tid = threadIdx.x;
  const int wv = tid >> 6, lane = tid & 63;

  int bid = blockIdx.x;
  int ty = (bid >= A.t[3].bstart) ? 3 : (bid >= A.t[2].bstart) ? 2
         : (bid >= A.t[1].bstart) ? 1 : 0;
  const TypeArgs& T = A.t[ty];
  const int rb = (bid - T.bstart) * 64;
  const int n = T.n;

  float4v acc[8];
  #pragma unroll
  for (int i = 0; i < 8; ++i) acc[i] = (float4v)0.0f;

  for (int kb = 0; kb < T.nsrc; ++kb) {
    const GemmSrc S = T.s[kb];
    if (S.cntBase < 0) {
      int r = tid >> 2, cb = (tid & 3) * 64;
      int g = rb + r;
      const short8v* p = (const short8v*)(S.xb + (size_t)g * 128 + (cb >> 1));
      #pragma unroll
      for (int k = 0; k < 4; ++k) {
        short8v h = (g < n) ? p[k] : (short8v)0;
        int byte = (r * 256 + cb + k * 16) ^ ((r & 7) << 4);
        *(short8v*)((char*)a_lds + byte) = h;
      }
    } else {
      const int r = tid >> 2;
      const int c0 = (tid & 3) * 32;
      int g = rb + r;
      int gd = S.cntBase + ((g < n) ? g : 0);
      int st = A.offs[gd];
      int deg = (g < n) ? A.cnt[gd] : 0;
      float4v a0 = (float4v)0.f, a1 = (float4v)0.f, a2 = (float4v)0.f,
              a3 = (float4v)0.f, a4 = (float4v)0.f, a5 = (float4v)0.f,
              a6 = (float4v)0.f, a7 = (float4v)0.f;
      int j = 0;
      for (; j + 2 <= deg; j += 2) {
        int i0 = A.csr[st + j], i1 = A.csr[st + j + 1];
        const short8v* p0 = (const short8v*)(S.xb + (size_t)i0 * 128 + c0);
        const short8v* p1 = (const short8v*)(S.xb + (size_t)i1 * 128 + c0);
        short8v h0 = p0[0], h1 = p0[1], h2 = p0[2], h3 = p0[3];
        short8v k0 = p1[0], k1 = p1[1], k2 = p1[2], k3 = p1[3];
        acc8(a0, a1, h0); acc8(a2, a3, h1); acc8(a4, a5, h2); acc8(a6, a7, h3);
        acc8(a0, a1, k0); acc8(a2, a3, k1); acc8(a4, a5, k2); acc8(a6, a7, k3);
      }
      if (j < deg) {
        int i0 = A.csr[st + j];
        const short8v* p0 = (const short8v*)(S.xb + (size_t)i0 * 128 + c0);
        short8v h0 = p0[0], h1 = p0[1], h2 = p0[2], h3 = p0[3];
        acc8(a0, a1, h0); acc8(a2, a3, h1); acc8(a4, a5, h2); acc8(a6, a7, h3);
      }
      float sc = 1.0f / (float)((deg > 0) ? deg : 1);
      a0 *= sc; a1 *= sc; a2 *= sc; a3 *= sc;
      a4 *= sc; a5 *= sc; a6 *= sc; a7 *= sc;
      short8v o0, o1, o2, o3;
      o0[0] = (short)f2bf(a0[0]); o0[1] = (short)f2bf(a0[1]);
      o0[2] = (short)f2bf(a0[2]); o0[3] = (short)f2bf(a0[3]);
      o0[4] = (short)f2bf(a1[0]); o0[5] = (short)f2bf(a1[1]);
      o0[6] = (short)f2bf(a1[2]); o0[7] = (short)f2bf(a1[3]);
      o1[0] = (short)f2bf(a2[0]); o1[1] = (short)f2bf(a2[1]);
      o1[2] = (short)f2bf(a2[2]); o1[3] = (short)f2bf(a2[3]);
      o1[4] = (short)f2bf(a3[0]); o1[5] = (short)f2bf(a3[1]);
      o1[6] = (short)f2bf(a3[2]); o1[7] = (short)f2bf(a3[3]);
      o2[0] = (short)f2bf(a4[0]); o2[1] = (short)f2bf(a4[1]);
      o2[2] = (short)f2bf(a4[2]); o2[3] = (short)f2bf(a4[3]);
      o2[4] = (short)f2bf(a5[0]); o2[5] = (short)f2bf(a5[1]);
      o2[6] = (short)f2bf(a5[2]); o2[7] = (short)f2bf(a5[3]);
      o3[0] = (short)f2bf(a6[0]); o3[1] = (short)f2bf(a6[1]);
      o3[2] = (short)f2bf(a6[2]); o3[3] = (short)f2bf(a6[3]);
      o3[4] = (short)f2bf(a7[0]); o3[5] = (short)f2bf(a7[1]);
      o3[6] = (short)f2bf(a7[2]); o3[7] = (short)f2bf(a7[3]);
      int bbase = r * 256 + c0 * 2;
      int sw = (r & 7) << 4;
      *(short8v*)((char*)a_lds + ((bbase) ^ sw)) = o0;
      *(short8v*)((char*)a_lds + ((bbase + 16) ^ sw)) = o1;
      *(short8v*)((char*)a_lds + ((bbase + 32) ^ sw)) = o2;
      *(short8v*)((char*)a_lds + ((bbase + 48) ^ sw)) = o3;
    }
    __syncthreads();
    short8v af[4];
    #pragma unroll
    for (int ks = 0; ks < 4; ++ks) {
      int r = wv * 16 + (lane & 15);
      int ch = ks * 4 + (lane >> 4);
      int byte = r * 256 + ch * 16; byte ^= (r & 7) << 4;
      af[ks] = *(const short8v*)((const char*)a_lds + byte);
    }
    const unsigned short* wbase = S.wt + (size_t)(lane & 15) * 128
                                + (size_t)(lane >> 4) * 8;
    #pragma unroll
    for (int ct = 0; ct < 8; ++ct) {
      short8v bfr[4];
      #pragma unroll
      for (int ks = 0; ks < 4; ++ks)
        bfr[ks] = *(const short8v*)(wbase + (size_t)ct * 16 * 128 + ks * 32);
      #pragma unroll
      for (int ks = 0; ks < 4; ++ks)
        acc[ct] = __builtin_amdgcn_mfma_f32_16x16x32_bf16(af[ks], bfr[ks], acc[ct], 0, 0, 0);
    }
    __syncthreads();
  }
  #pragma unroll
  for (int ct = 0; ct < 8; ++ct) {
    #pragma unroll
    for (int i = 0; i < 4; ++i) {
      int row = wv * 16 + (lane >> 4) * 4 + i;
      int g = rb + row;
      if (g < n) {
        int col = ct * 16 + (lane & 15);
        T.out[(size_t)g * 128 + col] = acc[ct][i] + T.bias[col];
      }
    }
  }
}

extern "C" void kernel_launch(void* const* d_in, const int* in_sizes, int n_in,
                              void* d_out, int out_size, void* d_ws, size_t ws_size,
                              hipStream_t stream) {
  const float* x_author = (const float*)d_in[0];
  const float* x_fos    = (const float*)d_in[1];
  const float* x_inst   = (const float*)d_in[2];
  const float* x_paper  = (const float*)d_in[3];

  Rels R;
  const int E[7]  = {150000, 150000, 500000, 500000, 1000000, 500000, 500000};
  const int ND[7] = {N_INST, N_AUTHOR, N_PAPER, N_AUTHOR, N_PAPER, N_FOS, N_PAPER};
  int base = 0;
  for (int r = 0; r < 7; ++r) {
    R.r[r].src = (const int*)d_in[4 + 2 * r];
    R.r[r].dst = (const int*)d_in[5 + 2 * r];
    R.r[r].E = E[r];
    R.r[r].base = base;
    base += ND[r];
  }

  char* ws = (char*)d_ws;
  int* cnt    = (int*)(ws + O_CNT);
  int* offs   = (int*)(ws + O_OFFS);
  int* cursor = (int*)(ws + O_CURSOR);   // bktCur in new path
  int* btot   = (int*)(ws + O_BTOT);
  int* csr    = (int*)(ws + O_CSR);
  unsigned short* wt = (unsigned short*)(ws + O_WT);
  unsigned short* xbA = (unsigned short*)(ws + XB_AUTHOR);
  unsigned short* xbF = (unsigned short*)(ws + XB_FOS);
  unsigned short* xbI = (unsigned short*)(ws + XB_INST);
  unsigned short* xbP = (unsigned short*)(ws + XB_PAPER);
  unsigned short* agg = (unsigned short*)(ws + O_AGG);

  const int useBF  = (ws_size >= WS_NEED_BF) ? 1 : 0;
  const int useAGG = (ws_size >= WS_NEED_AGG) ? 1 : 0;

  WPtrs WP;
  WP.w[0] = (const float*)d_in[18];
  WP.w[1] = (const float*)d_in[20];
  WP.w[2] = (const float*)d_in[22];
  WP.w[3] = (const float*)d_in[24];
  for (int r = 0; r < 7; ++r) WP.w[4 + r] = (const float*)d_in[26 + r];

  XCvt xcA = {x_author, xbA, N_AUTHOR * 16};
  XCvt xcF = {x_fos,    xbF, N_FOS * 16};
  XCvt xcI = {x_inst,   xbI, N_INST * 16};
  XCvt xcP = {x_paper,  xbP, N_PAPER * 16};

  hipMemsetAsync(cnt, 0, (size_t)NCNT * 4, stream);
  prep<<<2048, 256, 0, stream>>>(WP, wt, cnt, xcA, xcF, xcI, xcP, R, useBF);
  scan1<<<410, 256, 0, stream>>>(cnt, offs, btot, NCNT);
  scan23<<<1024, 512, 0, stream>>>(offs, cursor, btot, 410, NCNT);

  float* out = (float*)d_out;
  const int B_AFF = 0, B_ITA = 8000, B_WRITES = 108000, B_PTA = 308000,
            B_CITES = 408000, B_TOPIC = 608000, B_FTP = 638000;

  const int NB_AUTHOR = (N_AUTHOR + 63) / 64;
  const int NB_FOS    = (N_FOS + 63) / 64;
  const int NB_INST   = (N_INST + 63) / 64;
  const int NB_PAPER  = (N_PAPER + 63) / 64;
  const int NB_TOTAL = NB_AUTHOR + NB_FOS + NB_INST + NB_PAPER;

  float* outA = out;
  float* outF = out + (size_t)100000 * 128;
  float* outI = out + (size_t)130000 * 128;
  float* outP = out + (size_t)138000 * 128;
  const float* bA = (const float*)d_in[19];
  const float* bF = (const float*)d_in[21];
  const float* bI = (const float*)d_in[23];
  const float* bP = (const float*)d_in[25];

  if (useAGG) {
    // bucketed CSR build; pairs staged in d_out (overwritten by gemm later)
    uint2* pairs = (uint2*)d_out;
    c1_scatter<<<2048, 256, 0, stream>>>(R, cursor, pairs);
    c2_build<<<NBKT, 256, 0, stream>>>(pairs, offs, csr);

    agg_all<<<(NCNT + 3) / 4, 256, 0, stream>>>(xbA, xbF, xbI, xbP,
                                                offs, cnt, csr, agg);

    gemm_t<3><<<NB_AUTHOR, 256, 0, stream>>>(
        xbA, agg + (size_t)B_ITA * 128, agg + (size_t)B_PTA * 128, nullptr,
        wt + 0 * 16384, wt + 5 * 16384, wt + 7 * 16384, nullptr,
        bA, outA, N_AUTHOR);
    gemm_t<2><<<NB_FOS, 256, 0, stream>>>(
        xbF, agg + (size_t)B_TOPIC * 128, nullptr, nullptr,
        wt + 1 * 16384, wt + 9 * 16384, nullptr, nullptr,
        bF, outF, N_FOS);
    gemm_t<2><<<NB_INST, 256, 0, stream>>>(
        xbI, agg + (size_t)B_AFF * 128, nullptr, nullptr,
        wt + 2 * 16384, wt + 4 * 16384, nullptr, nullptr,
        bI, outI, N_INST);
    gemm_t<4><<<NB_PAPER, 256, 0, stream>>>(
        xbP, agg + (size_t)B_WRITES * 128, agg + (size_t)B_CITES * 128,
        agg + (size_t)B_FTP * 128,
        wt + 3 * 16384, wt + 6 * 16384, wt + 8 * 16384, wt + 10 * 16384,
        bP, outP, N_PAPER);
  } else {
    cpy_cursor<<<(NCNT + 255) / 256, 256, 0, stream>>>(offs, cursor);
    fill_k<<<2048, 256, 0, stream>>>(R, cursor, csr);

    AllArgs A;
    A.offs = offs; A.cnt = cnt; A.csr = csr;
    for (int t = 0; t < 4; ++t)
      for (int i = 0; i < 4; ++i) A.t[t].s[i] = GemmSrc{nullptr, nullptr, nullptr, 0};

    A.t[0].s[0] = GemmSrc{x_author, xbA, wt + 0 * 16384, -1};
    A.t[0].s[1] = GemmSrc{x_inst,   xbI, wt + 5 * 16384, B_ITA};
    A.t[0].s[2] = GemmSrc{x_paper,  xbP, wt + 7 * 16384, B_PTA};
    A.t[0].nsrc = 3; A.t[0].bstart = 0; A.t[0].n = N_AUTHOR;
    A.t[0].bias = bA; A.t[0].out = outA;

    A.t[1].s[0] = GemmSrc{x_fos,   xbF, wt + 1 * 16384, -1};
    A.t[1].s[1] = GemmSrc{x_paper, xbP, wt + 9 * 16384, B_TOPIC};
    A.t[1].nsrc = 2; A.t[1].bstart = NB_AUTHOR; A.t[1].n = N_FOS;
    A.t[1].bias = bF; A.t[1].out = outF;

    A.t[2].s[0] = GemmSrc{x_inst,   xbI, wt + 2 * 16384, -1};
    A.t[2].s[1] = GemmSrc{x_author, xbA, wt + 4 * 16384, B_AFF};
    A.t[2].nsrc = 2; A.t[2].bstart = NB_AUTHOR + NB_FOS; A.t[2].n = N_INST;
    A.t[2].bias = bI; A.t[2].out = outI;

    A.t[3].s[0] = GemmSrc{x_paper,  xbP, wt + 3 * 16384, -1};
    A.t[3].s[1] = GemmSrc{x_author, xbA, wt + 6 * 16384, B_WRITES};
    A.t[3].s[2] = GemmSrc{x_paper,  xbP, wt + 8 * 16384, B_CITES};
    A.t[3].s[3] = GemmSrc{x_fos,    xbF, wt + 10 * 16384, B_FTP};
    A.t[3].nsrc = 4; A.t[3].bstart = NB_AUTHOR + NB_FOS + NB_INST; A.t[3].n = N_PAPER;
    A.t[3].bias = bP; A.t[3].out = outP;

    rgcn_gemm<<<NB_TOTAL, 256, 0, stream>>>(A);
  }
}

// Round 9
// 979.268 us; speedup vs baseline: 4.4235x; 4.4235x over previous
//
#include <hip/hip_runtime.h>

#define N_AUTHOR 100000
#define N_FOS    30000
#define N_INST   8000
#define N_PAPER  200000
#define NCNT     838000
#define ETOT     3300000

typedef __attribute__((ext_vector_type(8))) short short8v;
typedef __attribute__((ext_vector_type(4))) float float4v;

__device__ __forceinline__ unsigned short f2bf(float f) {
  unsigned u = __float_as_uint(f);
  u = u + 0x7fffu + ((u >> 16) & 1u);
  return (unsigned short)(u >> 16);
}
#define BF2F(s) __uint_as_float(((unsigned)(unsigned short)(s)) << 16)

__device__ __forceinline__ void acc8(float4v& x, float4v& y, short8v h) {
  x[0] += BF2F(h[0]); x[1] += BF2F(h[1]); x[2] += BF2F(h[2]); x[3] += BF2F(h[3]);
  y[0] += BF2F(h[4]); y[1] += BF2F(h[5]); y[2] += BF2F(h[6]); y[3] += BF2F(h[7]);
}

__device__ __forceinline__ short8v pack8(float4v a, float4v b) {
  short8v h;
  h[0] = (short)f2bf(a[0]); h[1] = (short)f2bf(a[1]);
  h[2] = (short)f2bf(a[2]); h[3] = (short)f2bf(a[3]);
  h[4] = (short)f2bf(b[0]); h[5] = (short)f2bf(b[1]);
  h[6] = (short)f2bf(b[2]); h[7] = (short)f2bf(b[3]);
  return h;
}

// ---------------- workspace layout (bytes) ----------------
#define O_CNT    0
#define O_OFFS   3352000
#define O_CURSOR 6704000
#define O_BTOT   10056000
#define O_CSR    10060096
#define O_WT     23260096
#define XB_AUTHOR 23620544
#define XB_FOS    49220544
#define XB_INST   56900544
#define XB_PAPER  58948544
#define WS_NEED_BF 110148544ULL

struct RelTab { const int* src; const int* dst; int E; int base; };
struct Rels { RelTab r[7]; };
struct WPtrs { const float* w[11]; };
struct XCvt { const float* x; unsigned short* xb; int n8; };

// merged prep: W transpose+bf16, x fp32->bf16, edge COUNT (cnt pre-zeroed)
__global__ void prep(WPtrs P, unsigned short* __restrict__ wt,
                     int* __restrict__ cnt, XCvt x0, XCvt x1, XCvt x2, XCvt x3,
                     Rels R, int doX) {
  int gsz = gridDim.x * blockDim.x;
  int gtid = blockIdx.x * blockDim.x + threadIdx.x;
  for (int i = gtid; i < 11 * 16384; i += gsz) {
    int mat = i >> 14, rem = i & 16383;
    int k = rem >> 7, n = rem & 127;
    wt[mat * 16384 + n * 128 + k] = f2bf(P.w[mat][rem]);
  }
  if (doX) {
    XCvt xc[4] = {x0, x1, x2, x3};
    #pragma unroll
    for (int a = 0; a < 4; ++a) {
      const float* xp = xc[a].x;
      short8v* xbp = (short8v*)xc[a].xb;
      int n8 = xc[a].n8;
      for (int i = gtid; i < n8; i += gsz) {
        float4v v0 = *(const float4v*)(xp + (size_t)i * 8);
        float4v v1 = *(const float4v*)(xp + (size_t)i * 8 + 4);
        xbp[i] = pack8(v0, v1);
      }
    }
  }
  #pragma unroll
  for (int rr = 0; rr < 7; ++rr) {
    const int* dst = R.r[rr].dst;
    int E = R.r[rr].E, base = R.r[rr].base;
    for (int e = gtid; e < E; e += gsz) atomicAdd(&cnt[base + dst[e]], 1);
  }
}

__global__ void scan1(const int* __restrict__ cnt, int* __restrict__ offs,
                      int* __restrict__ btot, int n) {
  __shared__ int sh[256];
  int tid = threadIdx.x;
  int base = blockIdx.x * 2048 + tid * 8;
  int v[8]; int s = 0;
  #pragma unroll
  for (int i = 0; i < 8; ++i) { v[i] = (base + i < n) ? cnt[base + i] : 0; s += v[i]; }
  sh[tid] = s; __syncthreads();
  for (int off = 1; off < 256; off <<= 1) {
    int t = (tid >= off) ? sh[tid - off] : 0;
    __syncthreads();
    sh[tid] += t;
    __syncthreads();
  }
  int excl = sh[tid] - s;
  if (tid == 255) btot[blockIdx.x] = sh[255];
  int run = excl;
  #pragma unroll
  for (int i = 0; i < 8; ++i) { if (base + i < n) offs[base + i] = run; run += v[i]; }
}

__global__ void scan23(int* __restrict__ offs, int* __restrict__ cursor,
                       const int* __restrict__ btot, int nb, int n) {
  __shared__ int sh[512];
  int tid = threadIdx.x;
  int v = (tid < nb) ? btot[tid] : 0;
  sh[tid] = v; __syncthreads();
  for (int off = 1; off < 512; off <<= 1) {
    int t = (tid >= off) ? sh[tid - off] : 0;
    __syncthreads();
    sh[tid] += t;
    __syncthreads();
  }
  int excl = sh[tid] - v;
  __syncthreads();
  sh[tid] = excl;
  __syncthreads();
  int gsz = gridDim.x * 512;
  for (int idx = blockIdx.x * 512 + tid; idx < n; idx += gsz) {
    int val = offs[idx] + sh[idx >> 11];
    offs[idx] = val;
    cursor[idx] = val;
  }
}

__global__ void fill_k(Rels R, int* __restrict__ cursor, int* __restrict__ csr) {
  int gsz = gridDim.x * blockDim.x;
  int gtid = blockIdx.x * blockDim.x + threadIdx.x;
  #pragma unroll
  for (int rr = 0; rr < 7; ++rr) {
    const int* src = R.r[rr].src;
    const int* dst = R.r[rr].dst;
    int E = R.r[rr].E, base = R.r[rr].base;
    for (int e = gtid; e < E; e += gsz) {
      int p = atomicAdd(&cursor[base + dst[e]], 1);
      __builtin_nontemporal_store(src[e], &csr[p]);
    }
  }
}

// ---------------- fused per-type gather-GEMM: no LDS, no barriers ----------
// Each wave owns 16 output rows. A fragments built directly in registers:
// lane holds row (lane&15), k-windows ks*32+ch*8 (ch = lane>>4).
// Lanes r, r+16, r+32, r+48 cover one contiguous 64B line per window -> the
// gather is fully coalesced at 64B granularity, 256B per edge total.
template <int NSRC>
__global__ __launch_bounds__(256, 4) void fused_t(
    const unsigned short* __restrict__ x0, const unsigned short* __restrict__ x1,
    const unsigned short* __restrict__ x2, const unsigned short* __restrict__ x3,
    const unsigned short* __restrict__ w0, const unsigned short* __restrict__ w1,
    const unsigned short* __restrict__ w2, const unsigned short* __restrict__ w3,
    int b1, int b2, int b3,
    const int* __restrict__ offs, const int* __restrict__ cnt,
    const int* __restrict__ csr,
    const float* __restrict__ bias, float* __restrict__ out, int n) {
  const int lane = threadIdx.x & 63;
  const int wv = threadIdx.x >> 6;
  const int rb = blockIdx.x * 64 + wv * 16;
  int ar = rb + (lane & 15); if (ar >= n) ar = n - 1;
  const int ch = lane >> 4;                 // 0..3
  const int cw = ch * 8;                    // lane's base column within window

  const unsigned short* xs[4] = {x0, x1, x2, x3};
  const unsigned short* wsp[4] = {w0, w1, w2, w3};
  const int bases[4] = {0, b1, b2, b3};

  float4v acc[8];
  #pragma unroll
  for (int i = 0; i < 8; ++i) acc[i] = (float4v)0.0f;

  #pragma unroll
  for (int kb = 0; kb < NSRC; ++kb) {
    short8v af[4];
    if (kb == 0) {
      // root: direct fragment load from own row
      const unsigned short* rp = xs[0] + (size_t)ar * 128 + cw;
      #pragma unroll
      for (int ks = 0; ks < 4; ++ks)
        af[ks] = *(const short8v*)(rp + ks * 32);
    } else {
      int gd = bases[kb] + ar;
      int st = offs[gd];
      int deg = cnt[gd];
      const unsigned short* xb = xs[kb];
      float4v a0[4], a1[4];
      #pragma unroll
      for (int ks = 0; ks < 4; ++ks) { a0[ks] = (float4v)0.f; a1[ks] = (float4v)0.f; }
      int j = 0;
      for (; j + 2 <= deg; j += 2) {
        int s0 = csr[st + j], s1 = csr[st + j + 1];
        const unsigned short* p0 = xb + (size_t)s0 * 128 + cw;
        const unsigned short* p1 = xb + (size_t)s1 * 128 + cw;
        #pragma unroll
        for (int ks = 0; ks < 4; ++ks) {
          short8v h0 = *(const short8v*)(p0 + ks * 32);
          short8v h1 = *(const short8v*)(p1 + ks * 32);
          acc8(a0[ks], a1[ks], h0);
          acc8(a0[ks], a1[ks], h1);
        }
      }
      if (j < deg) {
        int s0 = csr[st + j];
        const unsigned short* p0 = xb + (size_t)s0 * 128 + cw;
        #pragma unroll
        for (int ks = 0; ks < 4; ++ks) {
          short8v h0 = *(const short8v*)(p0 + ks * 32);
          acc8(a0[ks], a1[ks], h0);
        }
      }
      float sc = 1.0f / (float)((deg > 0) ? deg : 1);
      #pragma unroll
      for (int ks = 0; ks < 4; ++ks)
        af[ks] = pack8(a0[ks] * sc, a1[ks] * sc);
    }
    // MFMA against W_kb (L2-hot, 32KB)
    const unsigned short* wb = wsp[kb] + (size_t)(lane & 15) * 128 + cw;
    #pragma unroll
    for (int ct = 0; ct < 8; ++ct) {
      short8v bfr[4];
      #pragma unroll
      for (int ks = 0; ks < 4; ++ks)
        bfr[ks] = *(const short8v*)(wb + ct * 2048 + ks * 32);
      #pragma unroll
      for (int ks = 0; ks < 4; ++ks)
        acc[ct] = __builtin_amdgcn_mfma_f32_16x16x32_bf16(af[ks], bfr[ks], acc[ct], 0, 0, 0);
    }
  }
  #pragma unroll
  for (int ct = 0; ct < 8; ++ct) {
    #pragma unroll
    for (int i = 0; i < 4; ++i) {
      int g = rb + (lane >> 4) * 4 + i;
      if (g < n) {
        int col = ct * 16 + (lane & 15);
        out[(size_t)g * 128 + col] = acc[ct][i] + bias[col];
      }
    }
  }
}

// ---------------- fp32 LDS fallback (small ws) ------------------------------
typedef float4v f4;
__global__ __launch_bounds__(256, 4) void fb_gemm(
    const float* __restrict__ x0, const float* __restrict__ x1,
    const float* __restrict__ x2, const float* __restrict__ x3,
    const unsigned short* __restrict__ w0, const unsigned short* __restrict__ w1,
    const unsigned short* __restrict__ w2, const unsigned short* __restrict__ w3,
    int nsrc, int b1, int b2, int b3,
    const int* __restrict__ offs, const int* __restrict__ cnt,
    const int* __restrict__ csr,
    const float* __restrict__ bias, float* __restrict__ out, int n) {
  const int lane = threadIdx.x & 63;
  const int wv = threadIdx.x >> 6;
  const int rb = blockIdx.x * 64 + wv * 16;
  int ar = rb + (lane & 15); if (ar >= n) ar = n - 1;
  const int ch = lane >> 4, cw = ch * 8;
  const float* xs[4] = {x0, x1, x2, x3};
  const unsigned short* wsp[4] = {w0, w1, w2, w3};
  const int bases[4] = {0, b1, b2, b3};
  float4v acc[8];
  #pragma unroll
  for (int i = 0; i < 8; ++i) acc[i] = (float4v)0.0f;
  for (int kb = 0; kb < nsrc; ++kb) {
    short8v af[4];
    const float* xb = xs[kb];
    if (kb == 0) {
      const float* rp = xb + (size_t)ar * 128 + cw;
      #pragma unroll
      for (int ks = 0; ks < 4; ++ks) {
        f4 u = *(const f4*)(rp + ks * 32);
        f4 v = *(const f4*)(rp + ks * 32 + 4);
        af[ks] = pack8(u, v);
      }
    } else {
      int gd = bases[kb] + ar;
      int st = offs[gd];
      int deg = cnt[gd];
      f4 a0[4], a1[4];
      #pragma unroll
      for (int ks = 0; ks < 4; ++ks) { a0[ks] = (f4)0.f; a1[ks] = (f4)0.f; }
      for (int j = 0; j < deg; ++j) {
        int s0 = csr[st + j];
        const float* p0 = xb + (size_t)s0 * 128 + cw;
        #pragma unroll
        for (int ks = 0; ks < 4; ++ks) {
          a0[ks] += *(const f4*)(p0 + ks * 32);
          a1[ks] += *(const f4*)(p0 + ks * 32 + 4);
        }
      }
      float sc = 1.0f / (float)((deg > 0) ? deg : 1);
      #pragma unroll
      for (int ks = 0; ks < 4; ++ks)
        af[ks] = pack8(a0[ks] * sc, a1[ks] * sc);
    }
    const unsigned short* wb = wsp[kb] + (size_t)(lane & 15) * 128 + cw;
    #pragma unroll
    for (int ct = 0; ct < 8; ++ct) {
      short8v bfr[4];
      #pragma unroll
      for (int ks = 0; ks < 4; ++ks)
        bfr[ks] = *(const short8v*)(wb + ct * 2048 + ks * 32);
      #pragma unroll
      for (int ks = 0; ks < 4; ++ks)
        acc[ct] = __builtin_amdgcn_mfma_f32_16x16x32_bf16(af[ks], bfr[ks], acc[ct], 0, 0, 0);
    }
  }
  #pragma unroll
  for (int ct = 0; ct < 8; ++ct) {
    #pragma unroll
    for (int i = 0; i < 4; ++i) {
      int g = rb + (lane >> 4) * 4 + i;
      if (g < n) {
        int col = ct * 16 + (lane & 15);
        out[(size_t)g * 128 + col] = acc[ct][i] + bias[col];
      }
    }
  }
}

extern "C" void kernel_launch(void* const* d_in, const int* in_sizes, int n_in,
                              void* d_out, int out_size, void* d_ws, size_t ws_size,
                              hipStream_t stream) {
  const float* x_author = (const float*)d_in[0];
  const float* x_fos    = (const float*)d_in[1];
  const float* x_inst   = (const float*)d_in[2];
  const float* x_paper  = (const float*)d_in[3];

  Rels R;
  const int E[7]  = {150000, 150000, 500000, 500000, 1000000, 500000, 500000};
  const int ND[7] = {N_INST, N_AUTHOR, N_PAPER, N_AUTHOR, N_PAPER, N_FOS, N_PAPER};
  int base = 0;
  for (int r = 0; r < 7; ++r) {
    R.r[r].src = (const int*)d_in[4 + 2 * r];
    R.r[r].dst = (const int*)d_in[5 + 2 * r];
    R.r[r].E = E[r];
    R.r[r].base = base;
    base += ND[r];
  }

  char* ws = (char*)d_ws;
  int* cnt    = (int*)(ws + O_CNT);
  int* offs   = (int*)(ws + O_OFFS);
  int* cursor = (int*)(ws + O_CURSOR);
  int* btot   = (int*)(ws + O_BTOT);
  int* csr    = (int*)(ws + O_CSR);
  unsigned short* wt = (unsigned short*)(ws + O_WT);
  unsigned short* xbA = (unsigned short*)(ws + XB_AUTHOR);
  unsigned short* xbF = (unsigned short*)(ws + XB_FOS);
  unsigned short* xbI = (unsigned short*)(ws + XB_INST);
  unsigned short* xbP = (unsigned short*)(ws + XB_PAPER);

  const int useBF = (ws_size >= WS_NEED_BF) ? 1 : 0;

  WPtrs WP;
  WP.w[0] = (const float*)d_in[18];
  WP.w[1] = (const float*)d_in[20];
  WP.w[2] = (const float*)d_in[22];
  WP.w[3] = (const float*)d_in[24];
  for (int r = 0; r < 7; ++r) WP.w[4 + r] = (const float*)d_in[26 + r];

  XCvt xcA = {x_author, xbA, N_AUTHOR * 16};
  XCvt xcF = {x_fos,    xbF, N_FOS * 16};
  XCvt xcI = {x_inst,   xbI, N_INST * 16};
  XCvt xcP = {x_paper,  xbP, N_PAPER * 16};

  hipMemsetAsync(cnt, 0, (size_t)NCNT * 4, stream);
  prep<<<2048, 256, 0, stream>>>(WP, wt, cnt, xcA, xcF, xcI, xcP, R, useBF);
  scan1<<<410, 256, 0, stream>>>(cnt, offs, btot, NCNT);
  scan23<<<1024, 512, 0, stream>>>(offs, cursor, btot, 410, NCNT);
  fill_k<<<2048, 256, 0, stream>>>(R, cursor, csr);

  float* out = (float*)d_out;
  const int B_AFF = 0, B_ITA = 8000, B_WRITES = 108000, B_PTA = 308000,
            B_CITES = 408000, B_TOPIC = 608000, B_FTP = 638000;

  const int NB_AUTHOR = (N_AUTHOR + 63) / 64;
  const int NB_FOS    = (N_FOS + 63) / 64;
  const int NB_INST   = (N_INST + 63) / 64;
  const int NB_PAPER  = (N_PAPER + 63) / 64;

  float* outA = out;
  float* outF = out + (size_t)100000 * 128;
  float* outI = out + (size_t)130000 * 128;
  float* outP = out + (size_t)138000 * 128;
  const float* bA = (const float*)d_in[19];
  const float* bF = (const float*)d_in[21];
  const float* bI = (const float*)d_in[23];
  const float* bP = (const float*)d_in[25];

  if (useBF) {
    fused_t<3><<<NB_AUTHOR, 256, 0, stream>>>(
        xbA, xbI, xbP, nullptr,
        wt + 0 * 16384, wt + 5 * 16384, wt + 7 * 16384, nullptr,
        B_ITA, B_PTA, 0, offs, cnt, csr, bA, outA, N_AUTHOR);
    fused_t<2><<<NB_FOS, 256, 0, stream>>>(
        xbF, xbP, nullptr, nullptr,
        wt + 1 * 16384, wt + 9 * 16384, nullptr, nullptr,
        B_TOPIC, 0, 0, offs, cnt, csr, bF, outF, N_FOS);
    fused_t<2><<<NB_INST, 256, 0, stream>>>(
        xbI, xbA, nullptr, nullptr,
        wt + 2 * 16384, wt + 4 * 16384, nullptr, nullptr,
        B_AFF, 0, 0, offs, cnt, csr, bI, outI, N_INST);
    fused_t<4><<<NB_PAPER, 256, 0, stream>>>(
        xbP, xbA, xbP, xbF,
        wt + 3 * 16384, wt + 6 * 16384, wt + 8 * 16384, wt + 10 * 16384,
        B_WRITES, B_CITES, B_FTP, offs, cnt, csr, bP, outP, N_PAPER);
  } else {
    fb_gemm<<<NB_AUTHOR, 256, 0, stream>>>(
        x_author, x_inst, x_paper, nullptr,
        wt + 0 * 16384, wt + 5 * 16384, wt + 7 * 16384, nullptr,
        3, B_ITA, B_PTA, 0, offs, cnt, csr, bA, outA, N_AUTHOR);
    fb_gemm<<<NB_FOS, 256, 0, stream>>>(
        x_fos, x_paper, nullptr, nullptr,
        wt + 1 * 16384, wt + 9 * 16384, nullptr, nullptr,
        2, B_TOPIC, 0, 0, offs, cnt, csr, bF, outF, N_FOS);
    fb_gemm<<<NB_INST, 256, 0, stream>>>(
        x_inst, x_author, nullptr, nullptr,
        wt + 2 * 16384, wt + 4 * 16384, nullptr, nullptr,
        2, B_AFF, 0, 0, offs, cnt, csr, bI, outI, N_INST);
    fb_gemm<<<NB_PAPER, 256, 0, stream>>>(
        x_paper, x_author, x_paper, x_fos,
        wt + 3 * 16384, wt + 6 * 16384, wt + 8 * 16384, wt + 10 * 16384,
        4, B_WRITES, B_CITES, B_FTP, offs, cnt, csr, bP, outP, N_PAPER);
  }
}

// Round 10
// 928.630 us; speedup vs baseline: 4.6647x; 1.0545x over previous
//
#include <hip/hip_runtime.h>

#define N_AUTHOR 100000
#define N_FOS    30000
#define N_INST   8000
#define N_PAPER  200000
#define NCNT     838000
#define ETOT     3300000

#define NBA 1563   // (N_AUTHOR+63)/64
#define NBF 469
#define NBI 125
#define NBP 3125
#define NB_TOTAL (NBP + NBA + NBF + NBI)

#define B_AFF    0
#define B_ITA    8000
#define B_WRITES 108000
#define B_PTA    308000
#define B_CITES  408000
#define B_TOPIC  608000
#define B_FTP    638000

typedef __attribute__((ext_vector_type(8))) short short8v;
typedef __attribute__((ext_vector_type(4))) float float4v;
typedef unsigned short us;

__device__ __forceinline__ us f2bf(float f) {
  unsigned u = __float_as_uint(f);
  u = u + 0x7fffu + ((u >> 16) & 1u);
  return (us)(u >> 16);
}
#define BF2F(s) __uint_as_float(((unsigned)(us)(s)) << 16)

__device__ __forceinline__ void acc8(float4v& x, float4v& y, short8v h) {
  x[0] += BF2F(h[0]); x[1] += BF2F(h[1]); x[2] += BF2F(h[2]); x[3] += BF2F(h[3]);
  y[0] += BF2F(h[4]); y[1] += BF2F(h[5]); y[2] += BF2F(h[6]); y[3] += BF2F(h[7]);
}

__device__ __forceinline__ short8v pack8(float4v a, float4v b) {
  short8v h;
  h[0] = (short)f2bf(a[0]); h[1] = (short)f2bf(a[1]);
  h[2] = (short)f2bf(a[2]); h[3] = (short)f2bf(a[3]);
  h[4] = (short)f2bf(b[0]); h[5] = (short)f2bf(b[1]);
  h[6] = (short)f2bf(b[2]); h[7] = (short)f2bf(b[3]);
  return h;
}

// ---------------- workspace layout (bytes) ----------------
#define O_CNT    0
#define O_OFFS   3352000
#define O_CURSOR 6704000
#define O_BTOT   10056000
#define O_CSR    10060096
#define O_WT     23260096
#define XB_AUTHOR 23620544
#define XB_FOS    49220544
#define XB_INST   56900544
#define XB_PAPER  58948544
#define WS_NEED_BF 110148544ULL

struct RelTab { const int* src; const int* dst; int E; int base; };
struct Rels { RelTab r[7]; };
struct WPtrs { const float* w[11]; };
struct XCvt { const float* x; us* xb; int n8; };

__global__ void prep(WPtrs P, us* __restrict__ wt,
                     int* __restrict__ cnt, XCvt x0, XCvt x1, XCvt x2, XCvt x3,
                     Rels R, int doX) {
  int gsz = gridDim.x * blockDim.x;
  int gtid = blockIdx.x * blockDim.x + threadIdx.x;
  for (int i = gtid; i < 11 * 16384; i += gsz) {
    int mat = i >> 14, rem = i & 16383;
    int k = rem >> 7, n = rem & 127;
    wt[mat * 16384 + n * 128 + k] = f2bf(P.w[mat][rem]);
  }
  if (doX) {
    XCvt xc[4] = {x0, x1, x2, x3};
    #pragma unroll
    for (int a = 0; a < 4; ++a) {
      const float* xp = xc[a].x;
      short8v* xbp = (short8v*)xc[a].xb;
      int n8 = xc[a].n8;
      for (int i = gtid; i < n8; i += gsz) {
        float4v v0 = *(const float4v*)(xp + (size_t)i * 8);
        float4v v1 = *(const float4v*)(xp + (size_t)i * 8 + 4);
        xbp[i] = pack8(v0, v1);
      }
    }
  }
  #pragma unroll
  for (int rr = 0; rr < 7; ++rr) {
    const int* dst = R.r[rr].dst;
    int E = R.r[rr].E, base = R.r[rr].base;
    for (int e = gtid; e < E; e += gsz) atomicAdd(&cnt[base + dst[e]], 1);
  }
}

__global__ void scan1(const int* __restrict__ cnt, int* __restrict__ offs,
                      int* __restrict__ btot, int n) {
  __shared__ int sh[256];
  int tid = threadIdx.x;
  int base = blockIdx.x * 2048 + tid * 8;
  int v[8]; int s = 0;
  #pragma unroll
  for (int i = 0; i < 8; ++i) { v[i] = (base + i < n) ? cnt[base + i] : 0; s += v[i]; }
  sh[tid] = s; __syncthreads();
  for (int off = 1; off < 256; off <<= 1) {
    int t = (tid >= off) ? sh[tid - off] : 0;
    __syncthreads();
    sh[tid] += t;
    __syncthreads();
  }
  int excl = sh[tid] - s;
  if (tid == 255) btot[blockIdx.x] = sh[255];
  int run = excl;
  #pragma unroll
  for (int i = 0; i < 8; ++i) { if (base + i < n) offs[base + i] = run; run += v[i]; }
}

__global__ void scan23(int* __restrict__ offs, int* __restrict__ cursor,
                       const int* __restrict__ btot, int nb, int n) {
  __shared__ int sh[512];
  int tid = threadIdx.x;
  int v = (tid < nb) ? btot[tid] : 0;
  sh[tid] = v; __syncthreads();
  for (int off = 1; off < 512; off <<= 1) {
    int t = (tid >= off) ? sh[tid - off] : 0;
    __syncthreads();
    sh[tid] += t;
    __syncthreads();
  }
  int excl = sh[tid] - v;
  __syncthreads();
  sh[tid] = excl;
  __syncthreads();
  int gsz = gridDim.x * 512;
  for (int idx = blockIdx.x * 512 + tid; idx < n; idx += gsz) {
    int val = offs[idx] + sh[idx >> 11];
    offs[idx] = val;
    cursor[idx] = val;
  }
}

__global__ void fill_k(Rels R, int* __restrict__ cursor, int* __restrict__ csr) {
  int gsz = gridDim.x * blockDim.x;
  int gtid = blockIdx.x * blockDim.x + threadIdx.x;
  #pragma unroll
  for (int rr = 0; rr < 7; ++rr) {
    const int* src = R.r[rr].src;
    const int* dst = R.r[rr].dst;
    int E = R.r[rr].E, base = R.r[rr].base;
    for (int e = gtid; e < E; e += gsz) {
      int p = atomicAdd(&cursor[base + dst[e]], 1);
      __builtin_nontemporal_store(src[e], &csr[p]);
    }
  }
}

// ---------------- fused gather-GEMM body (compile-time args) ----------------
template <int NSRC>
__device__ __forceinline__ void fused_body(
    const us* __restrict__ x0, const us* __restrict__ x1,
    const us* __restrict__ x2, const us* __restrict__ x3,
    const us* __restrict__ w0, const us* __restrict__ w1,
    const us* __restrict__ w2, const us* __restrict__ w3,
    int b1, int b2, int b3,
    const int* __restrict__ offs, const int* __restrict__ cnt,
    const int* __restrict__ csr,
    const float* __restrict__ bias, float* __restrict__ out, int n, int rb0) {
  const int lane = threadIdx.x & 63;
  const int wv = threadIdx.x >> 6;
  const int rb = rb0 + wv * 16;
  int ar = rb + (lane & 15); if (ar >= n) ar = n - 1;
  const int cw = (lane >> 4) * 8;

  const us* xs[4] = {x0, x1, x2, x3};
  const us* wsp[4] = {w0, w1, w2, w3};
  const int bases[4] = {0, b1, b2, b3};

  float4v acc[8];
  #pragma unroll
  for (int i = 0; i < 8; ++i) acc[i] = (float4v)0.0f;

  #pragma unroll
  for (int kb = 0; kb < NSRC; ++kb) {
    short8v af[4];
    if (kb == 0) {
      const us* rp = xs[0] + (size_t)ar * 128 + cw;
      #pragma unroll
      for (int ks = 0; ks < 4; ++ks)
        af[ks] = *(const short8v*)(rp + ks * 32);
    } else {
      int gd = bases[kb] + ar;
      int st = offs[gd];
      int deg = cnt[gd];
      const us* xb = xs[kb];
      float4v a0[4], a1[4];
      #pragma unroll
      for (int ks = 0; ks < 4; ++ks) { a0[ks] = (float4v)0.f; a1[ks] = (float4v)0.f; }
      int j = 0;
      for (; j + 4 <= deg; j += 4) {
        // one idx wait, then 16 row-loads in flight
        int s0 = csr[st + j],     s1 = csr[st + j + 1];
        int s2 = csr[st + j + 2], s3 = csr[st + j + 3];
        const us* p0 = xb + (size_t)s0 * 128 + cw;
        const us* p1 = xb + (size_t)s1 * 128 + cw;
        const us* p2 = xb + (size_t)s2 * 128 + cw;
        const us* p3 = xb + (size_t)s3 * 128 + cw;
        #pragma unroll
        for (int ks = 0; ks < 4; ++ks) {
          short8v h0 = *(const short8v*)(p0 + ks * 32);
          short8v h1 = *(const short8v*)(p1 + ks * 32);
          short8v h2 = *(const short8v*)(p2 + ks * 32);
          short8v h3 = *(const short8v*)(p3 + ks * 32);
          acc8(a0[ks], a1[ks], h0);
          acc8(a0[ks], a1[ks], h1);
          acc8(a0[ks], a1[ks], h2);
          acc8(a0[ks], a1[ks], h3);
        }
      }
      for (; j < deg; ++j) {
        int s0 = csr[st + j];
        const us* p0 = xb + (size_t)s0 * 128 + cw;
        #pragma unroll
        for (int ks = 0; ks < 4; ++ks) {
          short8v h0 = *(const short8v*)(p0 + ks * 32);
          acc8(a0[ks], a1[ks], h0);
        }
      }
      float sc = 1.0f / (float)((deg > 0) ? deg : 1);
      #pragma unroll
      for (int ks = 0; ks < 4; ++ks)
        af[ks] = pack8(a0[ks] * sc, a1[ks] * sc);
    }
    const us* wb = wsp[kb] + (size_t)(lane & 15) * 128 + cw;
    #pragma unroll
    for (int ct = 0; ct < 8; ++ct) {
      short8v bfr[4];
      #pragma unroll
      for (int ks = 0; ks < 4; ++ks)
        bfr[ks] = *(const short8v*)(wb + ct * 2048 + ks * 32);
      #pragma unroll
      for (int ks = 0; ks < 4; ++ks)
        acc[ct] = __builtin_amdgcn_mfma_f32_16x16x32_bf16(af[ks], bfr[ks], acc[ct], 0, 0, 0);
    }
  }
  #pragma unroll
  for (int ct = 0; ct < 8; ++ct) {
    #pragma unroll
    for (int i = 0; i < 4; ++i) {
      int g = rb + (lane >> 4) * 4 + i;
      if (g < n) {
        int col = ct * 16 + (lane & 15);
        __builtin_nontemporal_store(acc[ct][i] + bias[col],
                                    &out[(size_t)g * 128 + col]);
      }
    }
  }
}

// single merged launch; block ranges are compile-time; paper first (biggest)
__global__ __launch_bounds__(256, 6) void fused_all(
    const us* __restrict__ xbA, const us* __restrict__ xbF,
    const us* __restrict__ xbI, const us* __restrict__ xbP,
    const us* __restrict__ wt,
    const int* __restrict__ offs, const int* __restrict__ cnt,
    const int* __restrict__ csr,
    const float* __restrict__ bA, const float* __restrict__ bF,
    const float* __restrict__ bI, const float* __restrict__ bP,
    float* __restrict__ out) {
  const int bid = blockIdx.x;
  if (bid < NBP) {
    fused_body<4>(xbP, xbA, xbP, xbF,
                  wt + 3 * 16384, wt + 6 * 16384, wt + 8 * 16384, wt + 10 * 16384,
                  B_WRITES, B_CITES, B_FTP, offs, cnt, csr,
                  bP, out + (size_t)138000 * 128, N_PAPER, bid * 64);
  } else if (bid < NBP + NBA) {
    fused_body<3>(xbA, xbI, xbP, nullptr,
                  wt + 0 * 16384, wt + 5 * 16384, wt + 7 * 16384, nullptr,
                  B_ITA, B_PTA, 0, offs, cnt, csr,
                  bA, out, N_AUTHOR, (bid - NBP) * 64);
  } else if (bid < NBP + NBA + NBF) {
    fused_body<2>(xbF, xbP, nullptr, nullptr,
                  wt + 1 * 16384, wt + 9 * 16384, nullptr, nullptr,
                  B_TOPIC, 0, 0, offs, cnt, csr,
                  bF, out + (size_t)100000 * 128, N_FOS, (bid - NBP - NBA) * 64);
  } else {
    fused_body<2>(xbI, xbA, nullptr, nullptr,
                  wt + 2 * 16384, wt + 4 * 16384, nullptr, nullptr,
                  B_AFF, 0, 0, offs, cnt, csr,
                  bI, out + (size_t)130000 * 128, N_INST, (bid - NBP - NBA - NBF) * 64);
  }
}

// ---------------- fp32 fallback (small ws) ----------------------------------
typedef float4v f4;
__global__ __launch_bounds__(256, 4) void fb_gemm(
    const float* __restrict__ x0, const float* __restrict__ x1,
    const float* __restrict__ x2, const float* __restrict__ x3,
    const us* __restrict__ w0, const us* __restrict__ w1,
    const us* __restrict__ w2, const us* __restrict__ w3,
    int nsrc, int b1, int b2, int b3,
    const int* __restrict__ offs, const int* __restrict__ cnt,
    const int* __restrict__ csr,
    const float* __restrict__ bias, float* __restrict__ out, int n) {
  const int lane = threadIdx.x & 63;
  const int wv = threadIdx.x >> 6;
  const int rb = blockIdx.x * 64 + wv * 16;
  int ar = rb + (lane & 15); if (ar >= n) ar = n - 1;
  const int cw = (lane >> 4) * 8;
  const float* xs[4] = {x0, x1, x2, x3};
  const us* wsp[4] = {w0, w1, w2, w3};
  const int bases[4] = {0, b1, b2, b3};
  float4v acc[8];
  #pragma unroll
  for (int i = 0; i < 8; ++i) acc[i] = (float4v)0.0f;
  for (int kb = 0; kb < nsrc; ++kb) {
    short8v af[4];
    const float* xb = xs[kb];
    if (kb == 0) {
      const float* rp = xb + (size_t)ar * 128 + cw;
      #pragma unroll
      for (int ks = 0; ks < 4; ++ks) {
        f4 u = *(const f4*)(rp + ks * 32);
        f4 v = *(const f4*)(rp + ks * 32 + 4);
        af[ks] = pack8(u, v);
      }
    } else {
      int gd = bases[kb] + ar;
      int st = offs[gd];
      int deg = cnt[gd];
      f4 a0[4], a1[4];
      #pragma unroll
      for (int ks = 0; ks < 4; ++ks) { a0[ks] = (f4)0.f; a1[ks] = (f4)0.f; }
      for (int j = 0; j < deg; ++j) {
        int s0 = csr[st + j];
        const float* p0 = xb + (size_t)s0 * 128 + cw;
        #pragma unroll
        for (int ks = 0; ks < 4; ++ks) {
          a0[ks] += *(const f4*)(p0 + ks * 32);
          a1[ks] += *(const f4*)(p0 + ks * 32 + 4);
        }
      }
      float sc = 1.0f / (float)((deg > 0) ? deg : 1);
      #pragma unroll
      for (int ks = 0; ks < 4; ++ks)
        af[ks] = pack8(a0[ks] * sc, a1[ks] * sc);
    }
    const us* wb = wsp[kb] + (size_t)(lane & 15) * 128 + cw;
    #pragma unroll
    for (int ct = 0; ct < 8; ++ct) {
      short8v bfr[4];
      #pragma unroll
      for (int ks = 0; ks < 4; ++ks)
        bfr[ks] = *(const short8v*)(wb + ct * 2048 + ks * 32);
      #pragma unroll
      for (int ks = 0; ks < 4; ++ks)
        acc[ct] = __builtin_amdgcn_mfma_f32_16x16x32_bf16(af[ks], bfr[ks], acc[ct], 0, 0, 0);
    }
  }
  #pragma unroll
  for (int ct = 0; ct < 8; ++ct) {
    #pragma unroll
    for (int i = 0; i < 4; ++i) {
      int g = rb + (lane >> 4) * 4 + i;
      if (g < n) {
        int col = ct * 16 + (lane & 15);
        out[(size_t)g * 128 + col] = acc[ct][i] + bias[col];
      }
    }
  }
}

extern "C" void kernel_launch(void* const* d_in, const int* in_sizes, int n_in,
                              void* d_out, int out_size, void* d_ws, size_t ws_size,
                              hipStream_t stream) {
  const float* x_author = (const float*)d_in[0];
  const float* x_fos    = (const float*)d_in[1];
  const float* x_inst   = (const float*)d_in[2];
  const float* x_paper  = (const float*)d_in[3];

  Rels R;
  const int E[7]  = {150000, 150000, 500000, 500000, 1000000, 500000, 500000};
  const int ND[7] = {N_INST, N_AUTHOR, N_PAPER, N_AUTHOR, N_PAPER, N_FOS, N_PAPER};
  int base = 0;
  for (int r = 0; r < 7; ++r) {
    R.r[r].src = (const int*)d_in[4 + 2 * r];
    R.r[r].dst = (const int*)d_in[5 + 2 * r];
    R.r[r].E = E[r];
    R.r[r].base = base;
    base += ND[r];
  }

  char* ws = (char*)d_ws;
  int* cnt    = (int*)(ws + O_CNT);
  int* offs   = (int*)(ws + O_OFFS);
  int* cursor = (int*)(ws + O_CURSOR);
  int* btot   = (int*)(ws + O_BTOT);
  int* csr    = (int*)(ws + O_CSR);
  us* wt  = (us*)(ws + O_WT);
  us* xbA = (us*)(ws + XB_AUTHOR);
  us* xbF = (us*)(ws + XB_FOS);
  us* xbI = (us*)(ws + XB_INST);
  us* xbP = (us*)(ws + XB_PAPER);

  const int useBF = (ws_size >= WS_NEED_BF) ? 1 : 0;

  WPtrs WP;
  WP.w[0] = (const float*)d_in[18];
  WP.w[1] = (const float*)d_in[20];
  WP.w[2] = (const float*)d_in[22];
  WP.w[3] = (const float*)d_in[24];
  for (int r = 0; r < 7; ++r) WP.w[4 + r] = (const float*)d_in[26 + r];

  XCvt xcA = {x_author, xbA, N_AUTHOR * 16};
  XCvt xcF = {x_fos,    xbF, N_FOS * 16};
  XCvt xcI = {x_inst,   xbI, N_INST * 16};
  XCvt xcP = {x_paper,  xbP, N_PAPER * 16};

  hipMemsetAsync(cnt, 0, (size_t)NCNT * 4, stream);
  prep<<<2048, 256, 0, stream>>>(WP, wt, cnt, xcA, xcF, xcI, xcP, R, useBF);
  scan1<<<410, 256, 0, stream>>>(cnt, offs, btot, NCNT);
  scan23<<<1024, 512, 0, stream>>>(offs, cursor, btot, 410, NCNT);
  fill_k<<<2048, 256, 0, stream>>>(R, cursor, csr);

  float* out = (float*)d_out;
  const float* bA = (const float*)d_in[19];
  const float* bF = (const float*)d_in[21];
  const float* bI = (const float*)d_in[23];
  const float* bP = (const float*)d_in[25];

  if (useBF) {
    fused_all<<<NB_TOTAL, 256, 0, stream>>>(xbA, xbF, xbI, xbP, wt,
                                            offs, cnt, csr,
                                            bA, bF, bI, bP, out);
  } else {
    fb_gemm<<<NBA, 256, 0, stream>>>(
        x_author, x_inst, x_paper, nullptr,
        wt + 0 * 16384, wt + 5 * 16384, wt + 7 * 16384, nullptr,
        3, B_ITA, B_PTA, 0, offs, cnt, csr, bA, out, N_AUTHOR);
    fb_gemm<<<NBF, 256, 0, stream>>>(
        x_fos, x_paper, nullptr, nullptr,
        wt + 1 * 16384, wt + 9 * 16384, nullptr, nullptr,
        2, B_TOPIC, 0, 0, offs, cnt, csr, bF, out + (size_t)100000 * 128, N_FOS);
    fb_gemm<<<NBI, 256, 0, stream>>>(
        x_inst, x_author, nullptr, nullptr,
        wt + 2 * 16384, wt + 4 * 16384, nullptr, nullptr,
        2, B_AFF, 0, 0, offs, cnt, csr, bI, out + (size_t)130000 * 128, N_INST);
    fb_gemm<<<NBP, 256, 0, stream>>>(
        x_paper, x_author, x_paper, x_fos,
        wt + 3 * 16384, wt + 6 * 16384, wt + 8 * 16384, wt + 10 * 16384,
        4, B_WRITES, B_CITES, B_FTP, offs, cnt, csr, bP,
        out + (size_t)138000 * 128, N_PAPER);
  }
}